// Round 6
// baseline (6656.073 us; speedup 1.0000x reference)
//
#include <hip/hip_runtime.h>

#define NN 16384
#define MM 4096
#define DD 1024

typedef unsigned short u16;
typedef unsigned int u32;

enum { EPI_PLAIN = 0, EPI_MASK = 1, EPI_ELU = 2 };

// diagnostic: make absmax scream a known value
__global__ void sentinel_kernel(float* out, float val) {
    if (blockIdx.x == 0 && threadIdx.x < 64) out[threadIdx.x] = val;
}

// C[R,Cc] = A[R,K] * Bt[Cc,K]^T. All fp32. 128x128 tile, BK=16, 256 threads,
// 8x8 outputs/thread, +1-padded LDS. Pure VALU ground truth.
template <int EPI>
__global__ __launch_bounds__(256) void gemm_f32(
    const float* __restrict__ A, const float* __restrict__ Bt,
    float* __restrict__ C, const int* __restrict__ Hm,
    int Cc, int K)
{
    __shared__ float sA[128][17];
    __shared__ float sB[128][17];

    const int tid = threadIdx.x;
    const int tr = tid >> 4;          // 0..15
    const int tc = tid & 15;          // 0..15
    const int rowBlk = blockIdx.y * 128;
    const int colBlk = blockIdx.x * 128;
    const int sr = tid >> 1;          // staging row 0..127
    const int sk = (tid & 1) * 8;     // staging k offset {0,8}

    float acc[8][8] = {};

    for (int k0 = 0; k0 < K; k0 += 16) {
        const float* pa = A + (size_t)(rowBlk + sr) * K + k0 + sk;
        const float* pb = Bt + (size_t)(colBlk + sr) * K + k0 + sk;
        const float4 a0 = *(const float4*)pa;
        const float4 a1 = *(const float4*)(pa + 4);
        const float4 b0 = *(const float4*)pb;
        const float4 b1 = *(const float4*)(pb + 4);

        __syncthreads();              // prior iter fully consumed LDS
        sA[sr][sk + 0] = a0.x; sA[sr][sk + 1] = a0.y; sA[sr][sk + 2] = a0.z; sA[sr][sk + 3] = a0.w;
        sA[sr][sk + 4] = a1.x; sA[sr][sk + 5] = a1.y; sA[sr][sk + 6] = a1.z; sA[sr][sk + 7] = a1.w;
        sB[sr][sk + 0] = b0.x; sB[sr][sk + 1] = b0.y; sB[sr][sk + 2] = b0.z; sB[sr][sk + 3] = b0.w;
        sB[sr][sk + 4] = b1.x; sB[sr][sk + 5] = b1.y; sB[sr][sk + 6] = b1.z; sB[sr][sk + 7] = b1.w;
        __syncthreads();              // tile populated

#pragma unroll
        for (int k = 0; k < 16; ++k) {
            float fa[8], fb[8];
#pragma unroll
            for (int i = 0; i < 8; ++i) fa[i] = sA[tr * 8 + i][k];
#pragma unroll
            for (int j = 0; j < 8; ++j) fb[j] = sB[tc * 8 + j][k];
#pragma unroll
            for (int i = 0; i < 8; ++i)
#pragma unroll
                for (int j = 0; j < 8; ++j)
                    acc[i][j] = fmaf(fa[i], fb[j], acc[i][j]);
        }
    }

    const size_t ldc = (size_t)Cc;
#pragma unroll
    for (int i = 0; i < 8; ++i) {
        const int row = rowBlk + tr * 8 + i;
#pragma unroll
        for (int j = 0; j < 8; ++j) {
            const int col = colBlk + tc * 8 + j;
            float v = acc[i][j];
            if constexpr (EPI == EPI_MASK) {
                v *= 0.03125f;                               // 1/sqrt(1024)
                if (Hm[(size_t)row * ldc + col] <= 0) v = -1e9f;
            } else if constexpr (EPI == EPI_ELU) {
                v = v > 0.f ? v : (expf(v) - 1.f);
            }
            C[(size_t)row * ldc + col] = v;
        }
    }
}

// in-place masked softmax over rows of Bm [NN x MM] (fp32); masked entries hold -1e9
__global__ __launch_bounds__(256) void softmax_rows_f32(float* __restrict__ Bm)
{
    const int row = blockIdx.x;
    const int tid = threadIdx.x;
    const int lane = tid & 63;
    const int wid = tid >> 6;
    float4* rp = reinterpret_cast<float4*>(Bm + (size_t)row * MM);  // 1024 float4

    float4 q[4];
#pragma unroll
    for (int i = 0; i < 4; ++i) q[i] = rp[i * 256 + tid];           // coalesced
    float v[16];
#pragma unroll
    for (int i = 0; i < 4; ++i) {
        v[4 * i + 0] = q[i].x; v[4 * i + 1] = q[i].y;
        v[4 * i + 2] = q[i].z; v[4 * i + 3] = q[i].w;
    }

    float mx = -3e38f;
#pragma unroll
    for (int i = 0; i < 16; ++i) mx = fmaxf(mx, v[i]);
#pragma unroll
    for (int off = 32; off >= 1; off >>= 1) mx = fmaxf(mx, __shfl_xor(mx, off));
    __shared__ float red[4];
    if (lane == 0) red[wid] = mx;
    __syncthreads();
    mx = fmaxf(fmaxf(red[0], red[1]), fmaxf(red[2], red[3]));
    __syncthreads();

    float e[16];
    float s = 0.f;
#pragma unroll
    for (int i = 0; i < 16; ++i) { e[i] = expf(v[i] - mx); s += e[i]; }
#pragma unroll
    for (int off = 32; off >= 1; off >>= 1) s += __shfl_xor(s, off);
    if (lane == 0) red[wid] = s;
    __syncthreads();
    s = red[0] + red[1] + red[2] + red[3];
    const float inv = (mx > -1e8f && s > 0.f) ? (1.0f / s) : 0.f;   // all-masked row -> 0

#pragma unroll
    for (int i = 0; i < 4; ++i) {
        q[i].x = e[4 * i + 0] * inv; q[i].y = e[4 * i + 1] * inv;
        q[i].z = e[4 * i + 2] * inv; q[i].w = e[4 * i + 3] * inv;
        rp[i * 256 + tid] = q[i];
    }
}

extern "C" void kernel_launch(void* const* d_in, const int* in_sizes, int n_in,
                              void* d_out, int out_size, void* d_ws, size_t ws_size,
                              hipStream_t stream)
{
    (void)d_ws; (void)ws_size;

    float* O = (float*)d_out;                    // [NN*DD] output 0 (fp32)
    bool ok_sizes = (n_in == 5)
        && in_sizes[0] == NN * DD && in_sizes[1] == MM * DD
        && in_sizes[2] == NN * MM
        && in_sizes[3] == DD * DD && in_sizes[4] == DD * DD;
    if (!ok_sizes) { sentinel_kernel<<<1, 64, 0, stream>>>(O, 1e6f); return; }
    if (out_size != NN * DD + NN * MM) { sentinel_kernel<<<1, 64, 0, stream>>>(O, 2e6f); return; }

    const float* x  = (const float*)d_in[0];   // [NN, DD]
    const float* er = (const float*)d_in[1];   // [MM, DD]
    const int*   Hm = (const int*)d_in[2];     // [NN, MM]
    const float* We = (const float*)d_in[3];   // [DD, DD]
    const float* Wn = (const float*)d_in[4];   // [DD, DD]

    float* Bo = O + (size_t)NN * DD;             // [NN*MM] output 1 (fp32)

    // Scratch without d_ws (all fp32):
    //   hn  -> O (64 MB region, exact fit), dead when final GEMM overwrites O
    //   he  -> x's buffer (64 MB, dead after step 1; d_in restored each launch)
    //   heT -> x's buffer + MM*DD
    float* hn  = O;
    float* he  = (float*)d_in[0];
    float* heT = he + (size_t)MM * DD;           // he+heT = 33.6 MB <= 64 MB

    dim3 blk(256);
    // 1. hn = x @ W_n^T  (last use of x)             -> O
    gemm_f32<EPI_PLAIN><<<dim3(DD / 128, NN / 128), blk, 0, stream>>>(x, Wn, hn, nullptr, DD, DD);
    // 2. he = e_repr @ W_e^T                         -> x buffer
    gemm_f32<EPI_PLAIN><<<dim3(DD / 128, MM / 128), blk, 0, stream>>>(er, We, he, nullptr, DD, DD);
    // 3. S = (hn @ he^T)/32, masked                  -> Bo
    gemm_f32<EPI_MASK><<<dim3(MM / 128, NN / 128), blk, 0, stream>>>(hn, he, Bo, Hm, MM, DD);
    // 4. heT = W_e @ e_repr^T (= he^T)               -> x buffer + MM*DD
    gemm_f32<EPI_PLAIN><<<dim3(MM / 128, DD / 128), blk, 0, stream>>>(We, er, heT, nullptr, MM, DD);
    // 5. B = softmax(S) * mask, in place (fp32)
    softmax_rows_f32<<<dim3(NN), blk, 0, stream>>>(Bo);
    // 6. out = elu(B @ heT^T)                        -> O (hn dead)
    gemm_f32<EPI_ELU><<<dim3(DD / 128, NN / 128), blk, 0, stream>>>(Bo, heT, O, nullptr, DD, MM);
}